// Round 13
// baseline (310.664 us; speedup 1.0000x reference)
//
#include <hip/hip_runtime.h>

// ResidualVQ: Q=4, N_EMBED=1024, DIM=256, B=8, S=2048 (fp32).
// out = [quantized 8*2048*256][indices-as-float 4*8*2048][losses 4]
//
// R25: R24 confirmed the TA/coalescing theory (predicted 235-255, got 244).
// Re-evaluated under that model: R16's TM=16 @ (512,4) lost pre-cbT because
// doubled B-load instructions each cost 64-line TA serialization; cbT cuts
// that 4x. TM=16 buys TWO independent blocks/CU (acc[8]=32+bfr[8]=32 fits
// the 128-reg budget) whose barrier phases interleave — the overlap the
// monolith never had (R19's extra waves were same-block lockstep; R14's 2nd
// block was eaten by spill). This round: R16's verified structure + cbT
// B-loads + R24's k_prep/consolidation. Single substantive variable vs R24.
// Certified exact re-rank structure FROZEN (R11-R24): bf16-MFMA prefilter,
// tau margin 8x slack, frozen np fp32 distance chain, tie -> lower index,
// frozen STE recursion. Outputs bit-identical to R24/R16.
#define QQ   4
#define NE   1024
#define DIMD 256
#define MM   16384
#define TM   16
#define NW   8      // waves per block (512 threads)
#define CAP  32     // candidate slots per row (TM*CAP == 512)

typedef short v8s __attribute__((ext_vector_type(8)));   // 8 x bf16
typedef float v4f __attribute__((ext_vector_type(4)));

// ws layout (float offsets):
//  cbT   [QQ][8][NE][4][8] ushort @ 0     (524,288 floats)  [kc][code][quad]
//  bK    [QQ][NE]              @ 524,288  (4,096)
//  lossP double[QQ][64]        @ 528,384  (byte 2,113,536 %8==0; 512 floats)
//  done  uint                  @ 528,896

__device__ __forceinline__ unsigned short f2bf(float f) {  // RNE fp32->bf16
  unsigned u = __float_as_uint(f);
  return (unsigned short)((u + 0x7FFFu + ((u >> 16) & 1u)) >> 16);
}

// FROZEN numpy pairwise sumsq of 256 f32, over a 32-aligned group of 32 lanes
// (j = lane-in-group). Valid on j==0. Identical op tree/pairing as scalar.
__device__ __forceinline__ float np_sumsq_256_x32(const float* __restrict__ p,
                                                  int j) {
  const int bi = j >> 4, L = j & 15;
  const float* q = p + bi * 128 + L;
  float s0 = __fmul_rn(q[0], q[0]);
  float s1 = __fmul_rn(q[16], q[16]);
  float s2 = __fmul_rn(q[32], q[32]);
  float s3 = __fmul_rn(q[48], q[48]);
  float s4 = __fmul_rn(q[64], q[64]);
  float s5 = __fmul_rn(q[80], q[80]);
  float s6 = __fmul_rn(q[96], q[96]);
  float s7 = __fmul_rn(q[112], q[112]);
  float w = __fadd_rn(__fadd_rn(__fadd_rn(s0, s1), __fadd_rn(s2, s3)),
                      __fadd_rn(__fadd_rn(s4, s5), __fadd_rn(s6, s7)));
  float u  = __fadd_rn(w,  __shfl_down(w, 8, 64));   // valid L<8
  float t  = __fadd_rn(u,  __shfl_down(u, 4, 64));   // valid L<4
  float r2 = __fadd_rn(t,  __shfl_down(t, 2, 64));   // valid L<2
  float bb = __fadd_rn(r2, __shfl_down(r2, 1, 64));  // valid L==0 -> blk[bi]
  return __fadd_rn(bb, __shfl_down(bb, 16, 64));     // valid j==0
}

// frozen np distance, float4-load pipelined (IDENTICAL fma sequence/order)
__device__ __forceinline__ float np_dist_f4(const float* __restrict__ xp,
                                            const float* __restrict__ ep,
                                            float a, float b) {
  float m = 0.f;
  #pragma unroll 16
  for (int d4 = 0; d4 < DIMD / 4; ++d4) {
    const float4 xv = *(const float4*)(xp + d4 * 4);
    const float4 ev = *(const float4*)(ep + d4 * 4);
    m = fmaf(xv.x, ev.x, m);
    m = fmaf(xv.y, ev.y, m);
    m = fmaf(xv.z, ev.z, m);
    m = fmaf(xv.w, ev.w, m);
  }
  return __fadd_rn(__fsub_rn(a, __fmul_rn(2.0f, m)), b);
}

// prep: LDS-stage 8 codebook rows/block (R22/R24-verified pattern) -> bK
// (frozen x32 tree on identical bits) + TRANSPOSED bf16 cbT[kc][code][quad].
// 512 blocks x 256 threads; 8 | 1024 so a block never straddles qi.
__global__ __launch_bounds__(256) void k_prep(const float* __restrict__ cb,
                                              unsigned short* __restrict__ cbT,
                                              float* __restrict__ bK,
                                              double* __restrict__ lossP,
                                              unsigned* __restrict__ done) {
  __shared__ float rowS[8][256];
  const int t = threadIdx.x;
  const int Rbase = blockIdx.x * 8;                  // flat row (qi*NE+code)
  const size_t base = (size_t)Rbase * DIMD;
  {  // coalesced global->LDS: 512 float4, 2 per thread
    const float4* src = (const float4*)(cb + base);
    float4* dst = (float4*)rowS;
    dst[t] = src[t];
    dst[t + 256] = src[t + 256];
  }
  __syncthreads();
  {  // bK: (row r=t>>5, lane j=t&31), frozen x32 tree
    const int r = t >> 5, j = t & 31;
    float b = np_sumsq_256_x32(&rowS[r][0], j);
    if (j == 0) bK[Rbase + r] = b;
  }
  {  // cbT: thread t -> kc=t>>5, s=t&31: code_r=s>>2, quad=s&3 (8 bf16 = 16B)
    const int kc = t >> 5, s = t & 31;
    const int code_r = s >> 2, quad = s & 3;
    const int qi = (Rbase + code_r) >> 10;
    const int code = (Rbase + code_r) & 1023;
    const float* p = &rowS[code_r][kc * 32 + quad * 8];
    unsigned short o[8];
    #pragma unroll
    for (int k = 0; k < 8; ++k) o[k] = f2bf(p[k]);
    unsigned short* dst = cbT + (size_t)qi * NE * DIMD +
                          ((size_t)kc * NE + code) * 32 + quad * 8;
    *(v8s*)dst = *(v8s*)o;
  }
  if (blockIdx.x == 0) lossP[t] = 0.0;               // QQ*64 == 256 slots
  if (blockIdx.x == 0 && t == 0) *done = 0u;
}

// 512 threads = 8 waves; block owns TM=16 rows through ALL 4 stages; 1024
// blocks, launch_bounds(512,4) -> 128 regs/wave, TWO blocks/CU (acc[8]=32
// AGPR + bfr[8]=32 VGPR fit). Wave w covers codes [w*128,(w+1)*128).
__global__ __launch_bounds__(512, 4) void k_fused(
    const float* __restrict__ x,              // [MM][DIMD]
    const unsigned short* __restrict__ cbTa,  // [QQ][8][NE][4][8] bf16
    const float* __restrict__ cba,            // [QQ][NE][DIMD] fp32
    const float* __restrict__ bKa,            // [QQ][NE]
    double* __restrict__ lossP,               // [QQ][64]
    unsigned* __restrict__ doneCnt,           // grid done counter
    float* __restrict__ out_q,                // [MM][DIMD]
    float* __restrict__ idx_out,              // [QQ][MM] floats
    float* __restrict__ out_loss) {           // [QQ]
  __shared__ float residF[TM][DIMD + 4];       // fp32 residual, all 4 stages
  __shared__ unsigned short sX[TM][DIMD + 8];  // bf16 rows
  __shared__ float  sBK[NE];                   // bK staged per stage
  __shared__ float  av_s[TM];
  __shared__ float  candD[TM][NW];
  __shared__ float  thrS[TM];
  __shared__ int    cnt[TM];
  __shared__ int    candL[TM][CAP];
  __shared__ float  dcD[TM][CAP];
  __shared__ int    bcode[TM];
  __shared__ float  fwD[NW];
  __shared__ int    fwI[NW];
  __shared__ double lossW[NW];

  const int tid  = threadIdx.x;
  const int lane = tid & 63;
  const int wv   = tid >> 6;
  const int rowBase = blockIdx.x * TM;
  const int r32 = tid >> 5;        // row 0..15 (32 threads per row)
  const int j32 = tid & 31;        // lane in row-group
  const int d0  = j32 * 8;         // 8 floats per thread per row
  const int m16  = lane & 15;
  const int quad = lane >> 4;

  // x -> residF (exact fp32; stage-0 residual == x)
  {
    const float* xp = x + (size_t)(rowBase + r32) * DIMD + d0;
    *(float4*)&residF[r32][d0]     = *(const float4*)xp;
    *(float4*)&residF[r32][d0 + 4] = *(const float4*)(xp + 4);
  }
  __syncthreads();

  #pragma unroll 1
  for (int qi = 0; qi < QQ; ++qi) {
    const unsigned short* cbT = cbTa + (size_t)qi * NE * DIMD;
    const float* cb = cba + (size_t)qi * NE * DIMD;
    const float* bK = bKa + (size_t)qi * NE;

    // av (FROZEN, 32-lane tree, from LDS) + cnt reset + bK->LDS + bf16 staging
    {
      float av = np_sumsq_256_x32(&residF[r32][0], j32);
      if (j32 == 0) av_s[r32] = av;
    }
    if (tid < TM) cnt[tid] = 0;
    sBK[tid] = bK[tid];
    sBK[tid + 512] = bK[tid + 512];
    {
      const float* rp = &residF[r32][d0];
      const float4 f0 = *(const float4*)rp;
      const float4 f1 = *(const float4*)(rp + 4);
      unsigned short t[8] = {f2bf(f0.x), f2bf(f0.y), f2bf(f0.z), f2bf(f0.w),
                             f2bf(f1.x), f2bf(f1.y), f2bf(f1.z), f2bf(f1.w)};
      *(v8s*)&sX[r32][d0] = *(v8s*)t;
    }
    __syncthreads();

    // per-wave bmax over sBK (fp32 fmax == old atomicMax value bit-exactly)
    float bmx;
    {
      float bm = sBK[lane];
      #pragma unroll
      for (int t = 1; t < 16; ++t) bm = fmaxf(bm, sBK[lane + t * 64]);
      #pragma unroll
      for (int off = 32; off; off >>= 1) bm = fmaxf(bm, __shfl_xor(bm, off, 64));
      bmx = bm;
    }

    // MFMA: M~[row][code] for 8 col-tiles; A from LDS; B from cbT — each
    // fragment-load instruction's 64 lanes cover one CONTIGUOUS 1KB block.
    // Fragment VALUES identical to row-major loads -> d~ bit-identical.
    v4f acc[8];
    #pragma unroll
    for (int ct = 0; ct < 8; ++ct) acc[ct] = (v4f)(0.f);
    const unsigned short* bptrT =
        cbT + (size_t)(wv * 128 + m16) * 32 + quad * 8;
    #pragma unroll
    for (int kc = 0; kc < 8; ++kc) {
      v8s bfr[8];
      #pragma unroll
      for (int ct = 0; ct < 8; ++ct)
        bfr[ct] = *(const v8s*)(bptrT + (size_t)kc * (NE * 32) + ct * 512);
      v8s afr = *(const v8s*)&sX[m16][kc * 32 + quad * 8];
      #pragma unroll
      for (int ct = 0; ct < 8; ++ct)
        acc[ct] = __builtin_amdgcn_mfma_f32_16x16x32_bf16(afr, bfr[ct], acc[ct], 0, 0, 0);
    }

    // approx dist in-place: d~ = a - 2*M~ + b   (D: row=quad*4+v, col=m16)
    float av4[4];
    #pragma unroll
    for (int v = 0; v < 4; ++v) av4[v] = av_s[quad * 4 + v];
    #pragma unroll
    for (int ct = 0; ct < 8; ++ct) {
      const float bv = sBK[wv * 128 + ct * 16 + m16];
      #pragma unroll
      for (int v = 0; v < 4; ++v) acc[ct][v] = av4[v] - 2.0f * acc[ct][v] + bv;
    }

    // per-row min: over ct, then across the 16 lanes of each quad
    float vmin[4];
    #pragma unroll
    for (int v = 0; v < 4; ++v) {
      vmin[v] = acc[0][v];
      #pragma unroll
      for (int ct = 1; ct < 8; ++ct) vmin[v] = fminf(vmin[v], acc[ct][v]);
      #pragma unroll
      for (int off = 1; off < 16; off <<= 1)
        vmin[v] = fminf(vmin[v], __shfl_xor(vmin[v], off, 64));
    }
    if (m16 == 0) {
      #pragma unroll
      for (int v = 0; v < 4; ++v) candD[quad * 4 + v][wv] = vmin[v];
    }
    __syncthreads();
    if (tid < TM) {
      float bd = candD[tid][0];
      #pragma unroll
      for (int w = 1; w < NW; ++w) bd = fminf(bd, candD[tid][w]);
      // certified margin: 2*2^-8*sqrt(a*bmax) needed; 2^-5*sqrt(.)+0.1 = 8x slack
      thrS[tid] = bd + 0.03125f * sqrtf(av_s[tid] * bmx) + 0.1f;
    }
    __syncthreads();

    // gather candidates
    #pragma unroll
    for (int ct = 0; ct < 8; ++ct) {
      const int code = wv * 128 + ct * 16 + m16;
      #pragma unroll
      for (int v = 0; v < 4; ++v) {
        const int row = quad * 4 + v;
        if (acc[ct][v] <= thrS[row]) {
          int pos = atomicAdd(&cnt[row], 1);
          if (pos < CAP) candL[row][pos] = code;
        }
      }
    }
    __syncthreads();

    // exact (frozen) distance per candidate: one thread per (row, slot);
    // x-row from LDS (identical fp32 values, identical fma order)
    {
      const int n = (cnt[r32] <= CAP) ? cnt[r32] : 0;  // overflow -> fallback
      if (j32 < n) {
        const int code = candL[r32][j32];
        dcD[r32][j32] = np_dist_f4(&residF[r32][0], cb + (size_t)code * DIMD,
                                   av_s[r32], sBK[code]);
      }
    }
    __syncthreads();

    // cooperative fallback for overflow rows (rare): 2 codes/thread, exact
    for (int r = 0; r < TM; ++r) {
      if (cnt[r] > CAP) {
        const float* xp = &residF[r][0];
        const float a = av_s[r];
        float d1 = np_dist_f4(xp, cb + (size_t)tid * DIMD, a, sBK[tid]);
        float d2 = np_dist_f4(xp, cb + (size_t)(tid + 512) * DIMD, a, sBK[tid + 512]);
        int i1 = tid;
        if (d2 < d1) { d1 = d2; i1 = tid + 512; }  // strict <: lower idx on tie
        #pragma unroll
        for (int off = 32; off; off >>= 1) {
          float vd = __shfl_xor(d1, off, 64);
          int vi = __shfl_xor(i1, off, 64);
          if (vd < d1 || (vd == d1 && vi < i1)) { d1 = vd; i1 = vi; }
        }
        if (lane == 0) { fwD[wv] = d1; fwI[wv] = i1; }
        __syncthreads();
        if (tid == 0) {
          float bd = fwD[0];
          int bi = fwI[0];
          #pragma unroll
          for (int w = 1; w < NW; ++w) {
            if (fwD[w] < bd || (fwD[w] == bd && fwI[w] < bi)) {
              bd = fwD[w]; bi = fwI[w];
            }
          }
          bcode[r] = bi;
        }
        __syncthreads();
      }
    }

    if (tid < TM) {
      if (cnt[tid] <= CAP) {
        float bd = 3.4e38f;
        int bi = 0x7fffffff;
        for (int ci = 0; ci < cnt[tid]; ++ci) {
          float d = dcD[tid][ci];
          int code = candL[tid][ci];
          if (d < bd || (d == bd && code < bi)) { bd = d; bi = code; }
        }
        bcode[tid] = bi;
      }
      idx_out[(size_t)qi * MM + rowBase + tid] = (float)bcode[tid];
    }
    __syncthreads();

    // STE update — FROZEN: t=fl(q-r); u=fl(r+t); r'=fl(r-u)  (in-LDS)
    const int codeB = bcode[r32];
    double lsum = 0.0;
    #pragma unroll
    for (int h = 0; h < 2; ++h) {
      const int d = d0 + h * 4;
      const float4 ev = *(const float4*)(cb + (size_t)codeB * DIMD + d);
      const float4 rv = *(const float4*)&residF[r32][d];
      float t0 = __fsub_rn(ev.x, rv.x), u0 = __fadd_rn(rv.x, t0);
      float t1 = __fsub_rn(ev.y, rv.y), u1 = __fadd_rn(rv.y, t1);
      float t2 = __fsub_rn(ev.z, rv.z), u2 = __fadd_rn(rv.z, t2);
      float t3 = __fsub_rn(ev.w, rv.w), u3 = __fadd_rn(rv.w, t3);
      *(float4*)&residF[r32][d] =
          make_float4(__fsub_rn(rv.x, u0), __fsub_rn(rv.y, u1),
                      __fsub_rn(rv.z, u2), __fsub_rn(rv.w, u3));
      lsum += (double)__fmul_rn(t0, t0) + (double)__fmul_rn(t1, t1) +
              (double)__fmul_rn(t2, t2) + (double)__fmul_rn(t3, t3);
    }
    #pragma unroll
    for (int off = 32; off; off >>= 1) lsum += __shfl_xor(lsum, off, 64);
    if (lane == 0) lossW[wv] = lsum;
    __syncthreads();   // also orders residF writes before next stage's reads
    if (tid == 0) {
      double s = 0.0;
      #pragma unroll
      for (int w = 0; w < NW; ++w) s += lossW[w];
      atomicAdd(lossP + (size_t)qi * 64 + (blockIdx.x & 63), s);
    }
  }

  // epilogue: out_q = fl(x - resid_final)
  {
    const float* xp = x + (size_t)(rowBase + r32) * DIMD + d0;
    float* op = out_q + (size_t)(rowBase + r32) * DIMD + d0;
    const float4 a0 = *(const float4*)xp;
    const float4 a1 = *(const float4*)(xp + 4);
    const float4 b0 = *(const float4*)&residF[r32][d0];
    const float4 b1 = *(const float4*)&residF[r32][d0 + 4];
    *(float4*)op = make_float4(__fsub_rn(a0.x, b0.x), __fsub_rn(a0.y, b0.y),
                               __fsub_rn(a0.z, b0.z), __fsub_rn(a0.w, b0.w));
    *(float4*)(op + 4) = make_float4(__fsub_rn(a1.x, b1.x), __fsub_rn(a1.y, b1.y),
                                     __fsub_rn(a1.z, b1.z), __fsub_rn(a1.w, b1.w));
  }

  // folded k_loss: last block to finish sums lossP (device-scope atomics
  // both sides; __threadfence orders this block's lossP adds first).
  __syncthreads();
  if (tid == 0) {
    __threadfence();
    unsigned old = atomicAdd(doneCnt, 1u);
    cnt[0] = (old == (unsigned)(gridDim.x - 1)) ? 1 : 0;
  }
  __syncthreads();
  if (cnt[0] && tid < 64) {
    const int qi2 = tid >> 4;
    double s = 0.0;
    #pragma unroll
    for (int i = 0; i < 4; ++i)
      s += atomicAdd(lossP + (size_t)qi2 * 64 + (tid & 15) * 4 + i, 0.0);
    #pragma unroll
    for (int off = 8; off; off >>= 1) s += __shfl_down(s, off, 16);
    if ((tid & 15) == 0)
      out_loss[qi2] = (float)(s * (1.0 / (double)((size_t)MM * DIMD)));
  }
}

extern "C" void kernel_launch(void* const* d_in, const int* in_sizes, int n_in,
                              void* d_out, int out_size, void* d_ws, size_t ws_size,
                              hipStream_t stream) {
  const float* x = (const float*)d_in[0];        // [8,2048,256]
  const float* cb = (const float*)d_in[1];       // [4,1024,256]
  float* ws = (float*)d_ws;
  unsigned short* cbT = (unsigned short*)ws;     // 1,048,576 ushort (transposed)
  float* bK = ws + 524288;
  double* lossP = (double*)(ws + 528384);        // [QQ][64], byte off %8==0
  unsigned* done = (unsigned*)(ws + 528896);

  float* out = (float*)d_out;
  float* out_idx = out + (size_t)MM * DIMD;      // 4,194,304
  float* out_loss = out_idx + (size_t)QQ * MM;   // +65,536

  k_prep<<<dim3(QQ * NE / 8), dim3(256), 0, stream>>>(cb, cbT, bK, lossP, done);
  k_fused<<<dim3(MM / TM), dim3(512), 0, stream>>>(x, cbT, cb, bK, lossP,
                                                   done, out, out_idx, out_loss);
}

// Round 14
// 292.412 us; speedup vs baseline: 1.0624x; 1.0624x over previous
//
#include <hip/hip_runtime.h>

// ResidualVQ: Q=4, N_EMBED=1024, DIM=256, B=8, S=2048 (fp32).
// out = [quantized 8*2048*256][indices-as-float 4*8*2048][losses 4]
//
// R26 == R24 (verified best: 293us total / 244us k_fused). R25 falsified the
// cross-block-overlap theory (TM=16, 2 blocks/CU: occupancy 44% as predicted
// but k_fused 281us — B-load instruction doubling outweighs phase overlap).
// R24's structure: R18 monolith (TM=32, 512 thr, (512,2) no-spill, post-
// barrier gather, bfr[8] batch) + TRANSPOSED bf16 codebook cbT[kc][code][quad]
// so each MFMA B-fragment load instruction's 64 lanes cover one CONTIGUOUS
// 1KB block (16 cache lines/instr vs 64 row-major -> 4x less TA/address-unit
// serialization; the one confirmed-causal lever of the session: -35us,
// predicted 235-255, measured 244).
// Certified exact re-rank structure FROZEN (R11-R25): bf16-MFMA prefilter,
// tau margin 8x slack, frozen np fp32 distance chain, tie -> lower index,
// frozen STE recursion. Outputs bit-identical to R18/R24.
#define QQ   4
#define NE   1024
#define DIMD 256
#define MM   16384
#define TM   32
#define NW   8      // waves per block (512 threads)
#define CAP  32     // candidate slots per row

typedef short v8s __attribute__((ext_vector_type(8)));   // 8 x bf16
typedef float v4f __attribute__((ext_vector_type(4)));

// ws layout (float offsets):
//  cbT   [QQ][8][NE][4][8] ushort @ 0     (524,288 floats)  [kc][code][quad]
//  bK    [QQ][NE]              @ 524,288  (4,096)
//  lossP double[QQ][64]        @ 528,384  (byte 2,113,536 %8==0; 512 floats)
//  done  uint                  @ 528,896

__device__ __forceinline__ unsigned short f2bf(float f) {  // RNE fp32->bf16
  unsigned u = __float_as_uint(f);
  return (unsigned short)((u + 0x7FFFu + ((u >> 16) & 1u)) >> 16);
}

// FROZEN numpy pairwise sumsq of 256 f32, over a 32-aligned group of 32 lanes
// (j = lane-in-group). Valid on j==0. Identical op tree/pairing as scalar.
__device__ __forceinline__ float np_sumsq_256_x32(const float* __restrict__ p,
                                                  int j) {
  const int bi = j >> 4, L = j & 15;
  const float* q = p + bi * 128 + L;
  float s0 = __fmul_rn(q[0], q[0]);
  float s1 = __fmul_rn(q[16], q[16]);
  float s2 = __fmul_rn(q[32], q[32]);
  float s3 = __fmul_rn(q[48], q[48]);
  float s4 = __fmul_rn(q[64], q[64]);
  float s5 = __fmul_rn(q[80], q[80]);
  float s6 = __fmul_rn(q[96], q[96]);
  float s7 = __fmul_rn(q[112], q[112]);
  float w = __fadd_rn(__fadd_rn(__fadd_rn(s0, s1), __fadd_rn(s2, s3)),
                      __fadd_rn(__fadd_rn(s4, s5), __fadd_rn(s6, s7)));
  float u  = __fadd_rn(w,  __shfl_down(w, 8, 64));   // valid L<8
  float t  = __fadd_rn(u,  __shfl_down(u, 4, 64));   // valid L<4
  float r2 = __fadd_rn(t,  __shfl_down(t, 2, 64));   // valid L<2
  float bb = __fadd_rn(r2, __shfl_down(r2, 1, 64));  // valid L==0 -> blk[bi]
  return __fadd_rn(bb, __shfl_down(bb, 16, 64));     // valid j==0
}

// Same frozen tree over 16 lanes (j=0..15 in a 16-aligned group); bi serial.
// Operand pairing of every __fadd_rn identical to the scalar chain -> bit-exact.
__device__ __forceinline__ float np_sumsq_256_x16(const float* __restrict__ p,
                                                  int j) {
  float blk[2];
  #pragma unroll
  for (int bi = 0; bi < 2; ++bi) {
    const float* q = p + bi * 128 + j;
    float s0 = __fmul_rn(q[0], q[0]);
    float s1 = __fmul_rn(q[16], q[16]);
    float s2 = __fmul_rn(q[32], q[32]);
    float s3 = __fmul_rn(q[48], q[48]);
    float s4 = __fmul_rn(q[64], q[64]);
    float s5 = __fmul_rn(q[80], q[80]);
    float s6 = __fmul_rn(q[96], q[96]);
    float s7 = __fmul_rn(q[112], q[112]);
    float w = __fadd_rn(__fadd_rn(__fadd_rn(s0, s1), __fadd_rn(s2, s3)),
                        __fadd_rn(__fadd_rn(s4, s5), __fadd_rn(s6, s7)));
    float u  = __fadd_rn(w,  __shfl_down(w, 8, 64));   // valid j<8
    float t  = __fadd_rn(u,  __shfl_down(u, 4, 64));   // valid j<4
    float r2 = __fadd_rn(t,  __shfl_down(t, 2, 64));   // valid j<2
    blk[bi]  = __fadd_rn(r2, __shfl_down(r2, 1, 64));  // valid j==0
  }
  return __fadd_rn(blk[0], blk[1]);                    // valid j==0
}

// frozen np distance, float4-load pipelined (IDENTICAL fma sequence/order)
__device__ __forceinline__ float np_dist_f4(const float* __restrict__ xp,
                                            const float* __restrict__ ep,
                                            float a, float b) {
  float m = 0.f;
  #pragma unroll 16
  for (int d4 = 0; d4 < DIMD / 4; ++d4) {
    const float4 xv = *(const float4*)(xp + d4 * 4);
    const float4 ev = *(const float4*)(ep + d4 * 4);
    m = fmaf(xv.x, ev.x, m);
    m = fmaf(xv.y, ev.y, m);
    m = fmaf(xv.z, ev.z, m);
    m = fmaf(xv.w, ev.w, m);
  }
  return __fadd_rn(__fsub_rn(a, __fmul_rn(2.0f, m)), b);
}

// prep: LDS-stage 8 codebook rows/block (R22/R24-verified pattern) -> bK
// (frozen x32 tree on identical bits) + TRANSPOSED bf16 cbT[kc][code][quad].
// 512 blocks x 256 threads; 8 | 1024 so a block never straddles qi.
__global__ __launch_bounds__(256) void k_prep(const float* __restrict__ cb,
                                              unsigned short* __restrict__ cbT,
                                              float* __restrict__ bK,
                                              double* __restrict__ lossP,
                                              unsigned* __restrict__ done) {
  __shared__ float rowS[8][256];
  const int t = threadIdx.x;
  const int Rbase = blockIdx.x * 8;                  // flat row (qi*NE+code)
  const size_t base = (size_t)Rbase * DIMD;
  {  // coalesced global->LDS: 512 float4, 2 per thread
    const float4* src = (const float4*)(cb + base);
    float4* dst = (float4*)rowS;
    dst[t] = src[t];
    dst[t + 256] = src[t + 256];
  }
  __syncthreads();
  {  // bK: (row r=t>>5, lane j=t&31), frozen x32 tree
    const int r = t >> 5, j = t & 31;
    float b = np_sumsq_256_x32(&rowS[r][0], j);
    if (j == 0) bK[Rbase + r] = b;
  }
  {  // cbT: thread t -> kc=t>>5, s=t&31: code_r=s>>2, quad=s&3 (8 bf16 = 16B)
    const int kc = t >> 5, s = t & 31;
    const int code_r = s >> 2, quad = s & 3;
    const int qi = (Rbase + code_r) >> 10;
    const int code = (Rbase + code_r) & 1023;
    const float* p = &rowS[code_r][kc * 32 + quad * 8];
    unsigned short o[8];
    #pragma unroll
    for (int k = 0; k < 8; ++k) o[k] = f2bf(p[k]);
    unsigned short* dst = cbT + (size_t)qi * NE * DIMD +
                          ((size_t)kc * NE + code) * 32 + quad * 8;
    *(v8s*)dst = *(v8s*)o;
  }
  if (blockIdx.x == 0) lossP[t] = 0.0;               // QQ*64 == 256 slots
  if (blockIdx.x == 0 && t == 0) *done = 0u;
}

// 512 threads = 8 waves; block owns TM=32 rows through ALL 4 stages.
// Wave w covers codes [w*128,(w+1)*128): 8 col-tiles x 2 row-tiles.
// launch_bounds(512,2): 256 regs/wave -> acc[2][8]+bfr[8] fit, zero spill.
__global__ __launch_bounds__(512, 2) void k_fused(
    const float* __restrict__ x,              // [MM][DIMD]
    const unsigned short* __restrict__ cbTa,  // [QQ][8][NE][4][8] bf16
    const float* __restrict__ cba,            // [QQ][NE][DIMD] fp32
    const float* __restrict__ bKa,            // [QQ][NE]
    double* __restrict__ lossP,               // [QQ][64]
    unsigned* __restrict__ doneCnt,           // grid done counter
    float* __restrict__ out_q,                // [MM][DIMD]
    float* __restrict__ idx_out,              // [QQ][MM] floats
    float* __restrict__ out_loss) {           // [QQ]
  __shared__ float residF[TM][DIMD + 4];       // fp32 residual, all 4 stages
  __shared__ unsigned short sX[TM][DIMD + 8];  // bf16 rows
  __shared__ float  sBK[NE];                   // bK staged per stage
  __shared__ float  av_s[TM];
  __shared__ float  candD[TM][NW];
  __shared__ float  thrS[TM];
  __shared__ int    cnt[TM];
  __shared__ int    candL[TM][CAP];
  __shared__ float  dcD[TM][CAP];
  __shared__ int    bcode[TM];
  __shared__ float  fwD[NW];
  __shared__ int    fwI[NW];
  __shared__ double lossW[NW];

  const int tid  = threadIdx.x;
  const int lane = tid & 63;
  const int wv   = tid >> 6;
  const int rowBase = blockIdx.x * TM;
  const int r16 = tid >> 4;        // row 0..31 (16 threads per row)
  const int j16 = tid & 15;        // lane in row-group
  const int d0  = j16 * 16;        // 16 floats per thread per row
  const int m16  = lane & 15;
  const int quad = lane >> 4;

  // x -> residF (exact fp32; stage-0 residual == x)
  {
    const float* xp = x + (size_t)(rowBase + r16) * DIMD + d0;
    #pragma unroll
    for (int h = 0; h < 4; ++h)
      *(float4*)&residF[r16][d0 + h * 4] = *(const float4*)(xp + h * 4);
  }
  __syncthreads();

  #pragma unroll 1
  for (int qi = 0; qi < QQ; ++qi) {
    const unsigned short* cbT = cbTa + (size_t)qi * NE * DIMD;
    const float* cb = cba + (size_t)qi * NE * DIMD;
    const float* bK = bKa + (size_t)qi * NE;

    // av (FROZEN, 16-lane tree, from LDS) + cnt reset + bK->LDS + bf16 staging
    {
      float av = np_sumsq_256_x16(&residF[r16][0], j16);
      if (j16 == 0) av_s[r16] = av;
    }
    if (tid < TM) cnt[tid] = 0;
    sBK[tid] = bK[tid];
    sBK[tid + 512] = bK[tid + 512];
    {
      #pragma unroll
      for (int h = 0; h < 2; ++h) {
        const float* rp = &residF[r16][d0 + h * 8];
        const float4 f0 = *(const float4*)rp;
        const float4 f1 = *(const float4*)(rp + 4);
        unsigned short t[8] = {f2bf(f0.x), f2bf(f0.y), f2bf(f0.z), f2bf(f0.w),
                               f2bf(f1.x), f2bf(f1.y), f2bf(f1.z), f2bf(f1.w)};
        *(v8s*)&sX[r16][d0 + h * 8] = *(v8s*)t;
      }
    }
    __syncthreads();

    // per-wave bmax over sBK (fp32 fmax == old atomicMax value bit-exactly)
    float bmx;
    {
      float bm = sBK[lane];
      #pragma unroll
      for (int t = 1; t < 16; ++t) bm = fmaxf(bm, sBK[lane + t * 64]);
      #pragma unroll
      for (int off = 32; off; off >>= 1) bm = fmaxf(bm, __shfl_xor(bm, off, 64));
      bmx = bm;
    }

    // MFMA: M~[row][code], 2 row-tiles x 8 col-tiles per wave; per kc all 8
    // B-fragments batched. cbT layout: one fragment-load instruction's 64
    // lanes (m16*64B + quad*16B) cover a CONTIGUOUS 1KB block (16 lines).
    // Fragment VALUES identical to R18's row-major loads -> d~ bit-identical.
    v4f acc[2][8];
    #pragma unroll
    for (int mt = 0; mt < 2; ++mt)
      #pragma unroll
      for (int ct = 0; ct < 8; ++ct) acc[mt][ct] = (v4f)(0.f);
    const unsigned short* bptrT =
        cbT + (size_t)(wv * 128 + m16) * 32 + quad * 8;
    #pragma unroll
    for (int kc = 0; kc < 8; ++kc) {
      v8s bfr[8];
      #pragma unroll
      for (int ct = 0; ct < 8; ++ct)
        bfr[ct] = *(const v8s*)(bptrT + (size_t)kc * (NE * 32) + ct * 512);
      v8s a0 = *(const v8s*)&sX[m16][kc * 32 + quad * 8];
      v8s a1 = *(const v8s*)&sX[16 + m16][kc * 32 + quad * 8];
      #pragma unroll
      for (int ct = 0; ct < 8; ++ct) {
        acc[0][ct] = __builtin_amdgcn_mfma_f32_16x16x32_bf16(a0, bfr[ct], acc[0][ct], 0, 0, 0);
        acc[1][ct] = __builtin_amdgcn_mfma_f32_16x16x32_bf16(a1, bfr[ct], acc[1][ct], 0, 0, 0);
      }
    }

    // approx dist in-place: d~ = a - 2*M~ + b  (D: row=mt*16+quad*4+v, col=m16)
    float av8[2][4];
    #pragma unroll
    for (int mt = 0; mt < 2; ++mt)
      #pragma unroll
      for (int v = 0; v < 4; ++v) av8[mt][v] = av_s[mt * 16 + quad * 4 + v];
    #pragma unroll
    for (int ct = 0; ct < 8; ++ct) {
      const float bv = sBK[wv * 128 + ct * 16 + m16];
      #pragma unroll
      for (int mt = 0; mt < 2; ++mt)
        #pragma unroll
        for (int v = 0; v < 4; ++v)
          acc[mt][ct][v] = av8[mt][v] - 2.0f * acc[mt][ct][v] + bv;
    }

    // per-row min: over ct, then across the 16 lanes of each quad
    #pragma unroll
    for (int mt = 0; mt < 2; ++mt) {
      float vmin[4];
      #pragma unroll
      for (int v = 0; v < 4; ++v) {
        vmin[v] = acc[mt][0][v];
        #pragma unroll
        for (int ct = 1; ct < 8; ++ct) vmin[v] = fminf(vmin[v], acc[mt][ct][v]);
        #pragma unroll
        for (int off = 1; off < 16; off <<= 1)
          vmin[v] = fminf(vmin[v], __shfl_xor(vmin[v], off, 64));
      }
      if (m16 == 0) {
        #pragma unroll
        for (int v = 0; v < 4; ++v) candD[mt * 16 + quad * 4 + v][wv] = vmin[v];
      }
    }
    __syncthreads();
    if (tid < TM) {
      float bd = candD[tid][0];
      #pragma unroll
      for (int w = 1; w < NW; ++w) bd = fminf(bd, candD[tid][w]);
      // certified margin: 2*2^-8*sqrt(a*bmax) needed; 2^-5*sqrt(.)+0.1 = 8x slack
      thrS[tid] = bd + 0.03125f * sqrtf(av_s[tid] * bmx) + 0.1f;
    }
    __syncthreads();

    // gather candidates (acc stays live across the barrier; 256-reg budget
    // holds it without spill — R18-proven)
    #pragma unroll
    for (int ct = 0; ct < 8; ++ct) {
      const int code = wv * 128 + ct * 16 + m16;
      #pragma unroll
      for (int mt = 0; mt < 2; ++mt) {
        #pragma unroll
        for (int v = 0; v < 4; ++v) {
          const int row = mt * 16 + quad * 4 + v;
          if (acc[mt][ct][v] <= thrS[row]) {
            int pos = atomicAdd(&cnt[row], 1);
            if (pos < CAP) candL[row][pos] = code;
          }
        }
      }
    }
    __syncthreads();

    // exact (frozen) distance per candidate: thread (row, j16) covers slots
    // j16 and j16+16 (x from LDS: identical fp32 values, identical fma order)
    {
      const int n = (cnt[r16] <= CAP) ? cnt[r16] : 0;  // overflow -> fallback
      if (j16 < n) {
        const int code = candL[r16][j16];
        dcD[r16][j16] = np_dist_f4(&residF[r16][0], cb + (size_t)code * DIMD,
                                   av_s[r16], sBK[code]);
      }
      if (j16 + 16 < n) {
        const int code = candL[r16][j16 + 16];
        dcD[r16][j16 + 16] = np_dist_f4(&residF[r16][0], cb + (size_t)code * DIMD,
                                        av_s[r16], sBK[code]);
      }
    }
    __syncthreads();

    // cooperative fallback for overflow rows (rare): 2 codes/thread, exact
    for (int r = 0; r < TM; ++r) {
      if (cnt[r] > CAP) {
        const float* xp = &residF[r][0];
        const float a = av_s[r];
        float d1 = np_dist_f4(xp, cb + (size_t)tid * DIMD, a, sBK[tid]);
        float d2 = np_dist_f4(xp, cb + (size_t)(tid + 512) * DIMD, a, sBK[tid + 512]);
        int i1 = tid;
        if (d2 < d1) { d1 = d2; i1 = tid + 512; }  // strict <: lower idx on tie
        #pragma unroll
        for (int off = 32; off; off >>= 1) {
          float vd = __shfl_xor(d1, off, 64);
          int vi = __shfl_xor(i1, off, 64);
          if (vd < d1 || (vd == d1 && vi < i1)) { d1 = vd; i1 = vi; }
        }
        if (lane == 0) { fwD[wv] = d1; fwI[wv] = i1; }
        __syncthreads();
        if (tid == 0) {
          float bd = fwD[0];
          int bi = fwI[0];
          #pragma unroll
          for (int w = 1; w < NW; ++w) {
            if (fwD[w] < bd || (fwD[w] == bd && fwI[w] < bi)) {
              bd = fwD[w]; bi = fwI[w];
            }
          }
          bcode[r] = bi;
        }
        __syncthreads();
      }
    }

    if (tid < TM) {
      if (cnt[tid] <= CAP) {
        float bd = 3.4e38f;
        int bi = 0x7fffffff;
        for (int ci = 0; ci < cnt[tid]; ++ci) {
          float d = dcD[tid][ci];
          int code = candL[tid][ci];
          if (d < bd || (d == bd && code < bi)) { bd = d; bi = code; }
        }
        bcode[tid] = bi;
      }
      idx_out[(size_t)qi * MM + rowBase + tid] = (float)bcode[tid];
    }
    __syncthreads();

    // STE update — FROZEN: t=fl(q-r); u=fl(r+t); r'=fl(r-u)  (in-LDS)
    const int codeB = bcode[r16];
    double lsum = 0.0;
    #pragma unroll
    for (int h = 0; h < 4; ++h) {
      const int d = d0 + h * 4;
      const float4 ev = *(const float4*)(cb + (size_t)codeB * DIMD + d);
      const float4 rv = *(const float4*)&residF[r16][d];
      float t0 = __fsub_rn(ev.x, rv.x), u0 = __fadd_rn(rv.x, t0);
      float t1 = __fsub_rn(ev.y, rv.y), u1 = __fadd_rn(rv.y, t1);
      float t2 = __fsub_rn(ev.z, rv.z), u2 = __fadd_rn(rv.z, t2);
      float t3 = __fsub_rn(ev.w, rv.w), u3 = __fadd_rn(rv.w, t3);
      *(float4*)&residF[r16][d] =
          make_float4(__fsub_rn(rv.x, u0), __fsub_rn(rv.y, u1),
                      __fsub_rn(rv.z, u2), __fsub_rn(rv.w, u3));
      lsum += (double)__fmul_rn(t0, t0) + (double)__fmul_rn(t1, t1) +
              (double)__fmul_rn(t2, t2) + (double)__fmul_rn(t3, t3);
    }
    #pragma unroll
    for (int off = 32; off; off >>= 1) lsum += __shfl_xor(lsum, off, 64);
    if (lane == 0) lossW[wv] = lsum;
    __syncthreads();   // also orders residF writes before next stage's reads
    if (tid == 0) {
      double s = 0.0;
      #pragma unroll
      for (int w = 0; w < NW; ++w) s += lossW[w];
      atomicAdd(lossP + (size_t)qi * 64 + (blockIdx.x & 63), s);
    }
  }

  // epilogue: out_q = fl(x - resid_final)
  {
    const float* xp = x + (size_t)(rowBase + r16) * DIMD + d0;
    float* op = out_q + (size_t)(rowBase + r16) * DIMD + d0;
    #pragma unroll
    for (int h = 0; h < 4; ++h) {
      const float4 a = *(const float4*)(xp + h * 4);
      const float4 b = *(const float4*)&residF[r16][d0 + h * 4];
      *(float4*)(op + h * 4) =
          make_float4(__fsub_rn(a.x, b.x), __fsub_rn(a.y, b.y),
                      __fsub_rn(a.z, b.z), __fsub_rn(a.w, b.w));
    }
  }

  // folded k_loss: last block to finish sums lossP (device-scope atomics
  // both sides; __threadfence orders this block's lossP adds first).
  __syncthreads();
  if (tid == 0) {
    __threadfence();
    unsigned old = atomicAdd(doneCnt, 1u);
    cnt[0] = (old == (unsigned)(gridDim.x - 1)) ? 1 : 0;
  }
  __syncthreads();
  if (cnt[0] && tid < 64) {
    const int qi2 = tid >> 4;
    double s = 0.0;
    #pragma unroll
    for (int i = 0; i < 4; ++i)
      s += atomicAdd(lossP + (size_t)qi2 * 64 + (tid & 15) * 4 + i, 0.0);
    #pragma unroll
    for (int off = 8; off; off >>= 1) s += __shfl_down(s, off, 16);
    if ((tid & 15) == 0)
      out_loss[qi2] = (float)(s * (1.0 / (double)((size_t)MM * DIMD)));
  }
}

extern "C" void kernel_launch(void* const* d_in, const int* in_sizes, int n_in,
                              void* d_out, int out_size, void* d_ws, size_t ws_size,
                              hipStream_t stream) {
  const float* x = (const float*)d_in[0];        // [8,2048,256]
  const float* cb = (const float*)d_in[1];       // [4,1024,256]
  float* ws = (float*)d_ws;
  unsigned short* cbT = (unsigned short*)ws;     // 1,048,576 ushort (transposed)
  float* bK = ws + 524288;
  double* lossP = (double*)(ws + 528384);        // [QQ][64], byte off %8==0
  unsigned* done = (unsigned*)(ws + 528896);

  float* out = (float*)d_out;
  float* out_idx = out + (size_t)MM * DIMD;      // 4,194,304
  float* out_loss = out_idx + (size_t)QQ * MM;   // +65,536

  k_prep<<<dim3(QQ * NE / 8), dim3(256), 0, stream>>>(cb, cbT, bK, lossP, done);
  k_fused<<<dim3(MM / TM), dim3(512), 0, stream>>>(x, cbT, cb, bK, lossP,
                                                   done, out, out_idx, out_loss);
}

// Round 15
// 286.684 us; speedup vs baseline: 1.0836x; 1.0200x over previous
//
#include <hip/hip_runtime.h>

// ResidualVQ: Q=4, N_EMBED=1024, DIM=256, B=8, S=2048 (fp32).
// out = [quantized 8*2048*256][indices-as-float 4*8*2048][losses 4]
//
// R27: R26 (=R24, verified best 292us/242us k_fused) + register-neutral
// phase thinning (R23's fusion failed from register pressure; these add no
// cross-barrier state):
//  (1) thr phase removed: per-wave row-min -> order-preserving uint key ->
//      LDS atomicMin(rowMinU); after one barrier every thread decodes and
//      computes thr inline (textually identical fp expression -> same fp32;
//      -0/+0 ambiguity cancels in bd+tau). -1 barrier, -1 idle phase/stage.
//  (2) select fused into rerank: per-thread (d,code) pairs + 16-lane
//      lexicographic shfl reduce (R22-verified comparator == old serial
//      scan, order-independent). Removes serial tid<32 scan, dcD/candD
//      arrays, -1 barrier/stage. 7 -> 5 barriers/stage.
// Fallback/idx/STE ordering re-audited: every residF read->write transition
// stays barrier-separated (cnt[] is block-uniform so fallback's internal
// barriers are safe).
// Certified exact re-rank structure FROZEN (R11-R26): bf16-MFMA prefilter
// (cbT coalesced layout), tau margin 8x slack, frozen np fp32 distance
// chain, tie -> lower index, frozen STE recursion. Outputs bit-identical.
#define QQ   4
#define NE   1024
#define DIMD 256
#define MM   16384
#define TM   32
#define NW   8      // waves per block (512 threads)
#define CAP  32     // candidate slots per row

typedef short v8s __attribute__((ext_vector_type(8)));   // 8 x bf16
typedef float v4f __attribute__((ext_vector_type(4)));

// ws layout (float offsets):
//  cbT   [QQ][8][NE][4][8] ushort @ 0     (524,288 floats)  [kc][code][quad]
//  bK    [QQ][NE]              @ 524,288  (4,096)
//  lossP double[QQ][64]        @ 528,384  (byte 2,113,536 %8==0; 512 floats)
//  done  uint                  @ 528,896

__device__ __forceinline__ unsigned short f2bf(float f) {  // RNE fp32->bf16
  unsigned u = __float_as_uint(f);
  return (unsigned short)((u + 0x7FFFu + ((u >> 16) & 1u)) >> 16);
}

// FROZEN numpy pairwise sumsq of 256 f32, over a 32-aligned group of 32 lanes
// (j = lane-in-group). Valid on j==0. Identical op tree/pairing as scalar.
__device__ __forceinline__ float np_sumsq_256_x32(const float* __restrict__ p,
                                                  int j) {
  const int bi = j >> 4, L = j & 15;
  const float* q = p + bi * 128 + L;
  float s0 = __fmul_rn(q[0], q[0]);
  float s1 = __fmul_rn(q[16], q[16]);
  float s2 = __fmul_rn(q[32], q[32]);
  float s3 = __fmul_rn(q[48], q[48]);
  float s4 = __fmul_rn(q[64], q[64]);
  float s5 = __fmul_rn(q[80], q[80]);
  float s6 = __fmul_rn(q[96], q[96]);
  float s7 = __fmul_rn(q[112], q[112]);
  float w = __fadd_rn(__fadd_rn(__fadd_rn(s0, s1), __fadd_rn(s2, s3)),
                      __fadd_rn(__fadd_rn(s4, s5), __fadd_rn(s6, s7)));
  float u  = __fadd_rn(w,  __shfl_down(w, 8, 64));   // valid L<8
  float t  = __fadd_rn(u,  __shfl_down(u, 4, 64));   // valid L<4
  float r2 = __fadd_rn(t,  __shfl_down(t, 2, 64));   // valid L<2
  float bb = __fadd_rn(r2, __shfl_down(r2, 1, 64));  // valid L==0 -> blk[bi]
  return __fadd_rn(bb, __shfl_down(bb, 16, 64));     // valid j==0
}

// Same frozen tree over 16 lanes (j=0..15 in a 16-aligned group); bi serial.
// Operand pairing of every __fadd_rn identical to the scalar chain -> bit-exact.
__device__ __forceinline__ float np_sumsq_256_x16(const float* __restrict__ p,
                                                  int j) {
  float blk[2];
  #pragma unroll
  for (int bi = 0; bi < 2; ++bi) {
    const float* q = p + bi * 128 + j;
    float s0 = __fmul_rn(q[0], q[0]);
    float s1 = __fmul_rn(q[16], q[16]);
    float s2 = __fmul_rn(q[32], q[32]);
    float s3 = __fmul_rn(q[48], q[48]);
    float s4 = __fmul_rn(q[64], q[64]);
    float s5 = __fmul_rn(q[80], q[80]);
    float s6 = __fmul_rn(q[96], q[96]);
    float s7 = __fmul_rn(q[112], q[112]);
    float w = __fadd_rn(__fadd_rn(__fadd_rn(s0, s1), __fadd_rn(s2, s3)),
                        __fadd_rn(__fadd_rn(s4, s5), __fadd_rn(s6, s7)));
    float u  = __fadd_rn(w,  __shfl_down(w, 8, 64));   // valid j<8
    float t  = __fadd_rn(u,  __shfl_down(u, 4, 64));   // valid j<4
    float r2 = __fadd_rn(t,  __shfl_down(t, 2, 64));   // valid j<2
    blk[bi]  = __fadd_rn(r2, __shfl_down(r2, 1, 64));  // valid j==0
  }
  return __fadd_rn(blk[0], blk[1]);                    // valid j==0
}

// frozen np distance, float4-load pipelined (IDENTICAL fma sequence/order)
__device__ __forceinline__ float np_dist_f4(const float* __restrict__ xp,
                                            const float* __restrict__ ep,
                                            float a, float b) {
  float m = 0.f;
  #pragma unroll 16
  for (int d4 = 0; d4 < DIMD / 4; ++d4) {
    const float4 xv = *(const float4*)(xp + d4 * 4);
    const float4 ev = *(const float4*)(ep + d4 * 4);
    m = fmaf(xv.x, ev.x, m);
    m = fmaf(xv.y, ev.y, m);
    m = fmaf(xv.z, ev.z, m);
    m = fmaf(xv.w, ev.w, m);
  }
  return __fadd_rn(__fsub_rn(a, __fmul_rn(2.0f, m)), b);
}

// order-preserving float<->uint key (total order matching < on non-NaN)
__device__ __forceinline__ unsigned fkey_enc(float f) {
  unsigned b = __float_as_uint(f);
  return (b & 0x80000000u) ? ~b : (b | 0x80000000u);
}
__device__ __forceinline__ float fkey_dec(unsigned k) {
  unsigned b = (k & 0x80000000u) ? (k & 0x7FFFFFFFu) : ~k;
  return __uint_as_float(b);
}

// prep: LDS-stage 8 codebook rows/block (R22/R24-verified pattern) -> bK
// (frozen x32 tree on identical bits) + TRANSPOSED bf16 cbT[kc][code][quad].
// 512 blocks x 256 threads; 8 | 1024 so a block never straddles qi.
__global__ __launch_bounds__(256) void k_prep(const float* __restrict__ cb,
                                              unsigned short* __restrict__ cbT,
                                              float* __restrict__ bK,
                                              double* __restrict__ lossP,
                                              unsigned* __restrict__ done) {
  __shared__ float rowS[8][256];
  const int t = threadIdx.x;
  const int Rbase = blockIdx.x * 8;                  // flat row (qi*NE+code)
  const size_t base = (size_t)Rbase * DIMD;
  {  // coalesced global->LDS: 512 float4, 2 per thread
    const float4* src = (const float4*)(cb + base);
    float4* dst = (float4*)rowS;
    dst[t] = src[t];
    dst[t + 256] = src[t + 256];
  }
  __syncthreads();
  {  // bK: (row r=t>>5, lane j=t&31), frozen x32 tree
    const int r = t >> 5, j = t & 31;
    float b = np_sumsq_256_x32(&rowS[r][0], j);
    if (j == 0) bK[Rbase + r] = b;
  }
  {  // cbT: thread t -> kc=t>>5, s=t&31: code_r=s>>2, quad=s&3 (8 bf16 = 16B)
    const int kc = t >> 5, s = t & 31;
    const int code_r = s >> 2, quad = s & 3;
    const int qi = (Rbase + code_r) >> 10;
    const int code = (Rbase + code_r) & 1023;
    const float* p = &rowS[code_r][kc * 32 + quad * 8];
    unsigned short o[8];
    #pragma unroll
    for (int k = 0; k < 8; ++k) o[k] = f2bf(p[k]);
    unsigned short* dst = cbT + (size_t)qi * NE * DIMD +
                          ((size_t)kc * NE + code) * 32 + quad * 8;
    *(v8s*)dst = *(v8s*)o;
  }
  if (blockIdx.x == 0) lossP[t] = 0.0;               // QQ*64 == 256 slots
  if (blockIdx.x == 0 && t == 0) *done = 0u;
}

// 512 threads = 8 waves; block owns TM=32 rows through ALL 4 stages.
// Wave w covers codes [w*128,(w+1)*128): 8 col-tiles x 2 row-tiles.
// launch_bounds(512,2): 256 regs/wave -> acc[2][8]+bfr[8] fit, zero spill.
__global__ __launch_bounds__(512, 2) void k_fused(
    const float* __restrict__ x,              // [MM][DIMD]
    const unsigned short* __restrict__ cbTa,  // [QQ][8][NE][4][8] bf16
    const float* __restrict__ cba,            // [QQ][NE][DIMD] fp32
    const float* __restrict__ bKa,            // [QQ][NE]
    double* __restrict__ lossP,               // [QQ][64]
    unsigned* __restrict__ doneCnt,           // grid done counter
    float* __restrict__ out_q,                // [MM][DIMD]
    float* __restrict__ idx_out,              // [QQ][MM] floats
    float* __restrict__ out_loss) {           // [QQ]
  __shared__ float residF[TM][DIMD + 4];       // fp32 residual, all 4 stages
  __shared__ unsigned short sX[TM][DIMD + 8];  // bf16 rows
  __shared__ float  sBK[NE];                   // bK staged per stage
  __shared__ float  av_s[TM];
  __shared__ unsigned rowMinU[TM];             // order-preserving d~ min keys
  __shared__ int    cnt[TM];
  __shared__ int    candL[TM][CAP];
  __shared__ int    bcode[TM];
  __shared__ float  fwD[NW];
  __shared__ int    fwI[NW];
  __shared__ double lossW[NW];

  const int tid  = threadIdx.x;
  const int lane = tid & 63;
  const int wv   = tid >> 6;
  const int rowBase = blockIdx.x * TM;
  const int r16 = tid >> 4;        // row 0..31 (16 threads per row)
  const int j16 = tid & 15;        // lane in row-group
  const int d0  = j16 * 16;        // 16 floats per thread per row
  const int m16  = lane & 15;
  const int quad = lane >> 4;

  // x -> residF (exact fp32; stage-0 residual == x)
  {
    const float* xp = x + (size_t)(rowBase + r16) * DIMD + d0;
    #pragma unroll
    for (int h = 0; h < 4; ++h)
      *(float4*)&residF[r16][d0 + h * 4] = *(const float4*)(xp + h * 4);
  }
  __syncthreads();

  #pragma unroll 1
  for (int qi = 0; qi < QQ; ++qi) {
    const unsigned short* cbT = cbTa + (size_t)qi * NE * DIMD;
    const float* cb = cba + (size_t)qi * NE * DIMD;
    const float* bK = bKa + (size_t)qi * NE;

    // phase 1: av (FROZEN 16-lane tree) + cnt/rowMin reset + bK->LDS + bf16
    {
      float av = np_sumsq_256_x16(&residF[r16][0], j16);
      if (j16 == 0) av_s[r16] = av;
    }
    if (tid < TM) { cnt[tid] = 0; rowMinU[tid] = 0xFFFFFFFFu; }
    sBK[tid] = bK[tid];
    sBK[tid + 512] = bK[tid + 512];
    {
      #pragma unroll
      for (int h = 0; h < 2; ++h) {
        const float* rp = &residF[r16][d0 + h * 8];
        const float4 f0 = *(const float4*)rp;
        const float4 f1 = *(const float4*)(rp + 4);
        unsigned short t[8] = {f2bf(f0.x), f2bf(f0.y), f2bf(f0.z), f2bf(f0.w),
                               f2bf(f1.x), f2bf(f1.y), f2bf(f1.z), f2bf(f1.w)};
        *(v8s*)&sX[r16][d0 + h * 8] = *(v8s*)t;
      }
    }
    __syncthreads();

    // per-wave bmax over sBK (fp32 fmax == old atomicMax value bit-exactly)
    float bmx;
    {
      float bm = sBK[lane];
      #pragma unroll
      for (int t = 1; t < 16; ++t) bm = fmaxf(bm, sBK[lane + t * 64]);
      #pragma unroll
      for (int off = 32; off; off >>= 1) bm = fmaxf(bm, __shfl_xor(bm, off, 64));
      bmx = bm;
    }

    // phase 2: MFMA (cbT-coalesced B), d~, per-row wave-min -> atomicMin key
    v4f acc[2][8];
    #pragma unroll
    for (int mt = 0; mt < 2; ++mt)
      #pragma unroll
      for (int ct = 0; ct < 8; ++ct) acc[mt][ct] = (v4f)(0.f);
    const unsigned short* bptrT =
        cbT + (size_t)(wv * 128 + m16) * 32 + quad * 8;
    #pragma unroll
    for (int kc = 0; kc < 8; ++kc) {
      v8s bfr[8];
      #pragma unroll
      for (int ct = 0; ct < 8; ++ct)
        bfr[ct] = *(const v8s*)(bptrT + (size_t)kc * (NE * 32) + ct * 512);
      v8s a0 = *(const v8s*)&sX[m16][kc * 32 + quad * 8];
      v8s a1 = *(const v8s*)&sX[16 + m16][kc * 32 + quad * 8];
      #pragma unroll
      for (int ct = 0; ct < 8; ++ct) {
        acc[0][ct] = __builtin_amdgcn_mfma_f32_16x16x32_bf16(a0, bfr[ct], acc[0][ct], 0, 0, 0);
        acc[1][ct] = __builtin_amdgcn_mfma_f32_16x16x32_bf16(a1, bfr[ct], acc[1][ct], 0, 0, 0);
      }
    }

    // d~ = a - 2*M~ + b  (D: row=mt*16+quad*4+v, col=m16)
    float av8[2][4];
    #pragma unroll
    for (int mt = 0; mt < 2; ++mt)
      #pragma unroll
      for (int v = 0; v < 4; ++v) av8[mt][v] = av_s[mt * 16 + quad * 4 + v];
    #pragma unroll
    for (int ct = 0; ct < 8; ++ct) {
      const float bv = sBK[wv * 128 + ct * 16 + m16];
      #pragma unroll
      for (int mt = 0; mt < 2; ++mt)
        #pragma unroll
        for (int v = 0; v < 4; ++v)
          acc[mt][ct][v] = av8[mt][v] - 2.0f * acc[mt][ct][v] + bv;
    }

    // per-row wave-min over this wave's 128 codes -> atomicMin(key)
    #pragma unroll
    for (int mt = 0; mt < 2; ++mt) {
      float vmin[4];
      #pragma unroll
      for (int v = 0; v < 4; ++v) {
        vmin[v] = acc[mt][0][v];
        #pragma unroll
        for (int ct = 1; ct < 8; ++ct) vmin[v] = fminf(vmin[v], acc[mt][ct][v]);
        #pragma unroll
        for (int off = 1; off < 16; off <<= 1)
          vmin[v] = fminf(vmin[v], __shfl_xor(vmin[v], off, 64));
      }
      if (m16 == 0) {
        #pragma unroll
        for (int v = 0; v < 4; ++v)
          atomicMin(&rowMinU[mt * 16 + quad * 4 + v], fkey_enc(vmin[v]));
      }
    }
    __syncthreads();

    // phase 3: gather — thr computed inline (same fp expression/values as
    // the old tid<TM phase; acc stays live, R18-proven no-spill)
    float thrw[2][4];
    #pragma unroll
    for (int mt = 0; mt < 2; ++mt)
      #pragma unroll
      for (int v = 0; v < 4; ++v) {
        const float bd = fkey_dec(rowMinU[mt * 16 + quad * 4 + v]);
        // certified margin: 2*2^-8*sqrt(a*bmax) needed; 2^-5*sqrt(.)+0.1 = 8x
        thrw[mt][v] = bd + 0.03125f * sqrtf(av8[mt][v] * bmx) + 0.1f;
      }
    #pragma unroll
    for (int ct = 0; ct < 8; ++ct) {
      const int code = wv * 128 + ct * 16 + m16;
      #pragma unroll
      for (int mt = 0; mt < 2; ++mt) {
        #pragma unroll
        for (int v = 0; v < 4; ++v) {
          if (acc[mt][ct][v] <= thrw[mt][v]) {
            const int row = mt * 16 + quad * 4 + v;
            int pos = atomicAdd(&cnt[row], 1);
            if (pos < CAP) candL[row][pos] = code;
          }
        }
      }
    }
    __syncthreads();

    // phase 4: rerank + select fused. Thread (row,j16) covers slots j16 and
    // j16+16 (np_dist FROZEN, from LDS resid), then 16-lane lexicographic
    // (d, code) reduce == old serial scan (order-independent, tie->lower).
    {
      const int cv = cnt[r16];
      const int n = (cv <= CAP) ? cv : 0;   // overflow -> fallback path
      float bd = 3.4e38f;
      int bi = 0x7fffffff;
      if (j16 < n) {
        const int code = candL[r16][j16];
        bd = np_dist_f4(&residF[r16][0], cb + (size_t)code * DIMD,
                        av_s[r16], sBK[code]);
        bi = code;
      }
      if (j16 + 16 < n) {
        const int code2 = candL[r16][j16 + 16];
        float d2 = np_dist_f4(&residF[r16][0], cb + (size_t)code2 * DIMD,
                              av_s[r16], sBK[code2]);
        if (d2 < bd || (d2 == bd && code2 < bi)) { bd = d2; bi = code2; }
      }
      #pragma unroll
      for (int off = 8; off; off >>= 1) {
        float vd = __shfl_xor(bd, off, 64);
        int vi = __shfl_xor(bi, off, 64);
        if (vd < bd || (vd == bd && vi < bi)) { bd = vd; bi = vi; }
      }
      if (j16 == 0 && cv <= CAP) bcode[r16] = bi;
    }
    __syncthreads();

    // cooperative fallback for overflow rows (rare): 2 codes/thread, exact;
    // cnt[] is block-uniform so the internal barriers are safe.
    for (int r = 0; r < TM; ++r) {
      if (cnt[r] > CAP) {
        const float* xp = &residF[r][0];
        const float a = av_s[r];
        float d1 = np_dist_f4(xp, cb + (size_t)tid * DIMD, a, sBK[tid]);
        float d2 = np_dist_f4(xp, cb + (size_t)(tid + 512) * DIMD, a, sBK[tid + 512]);
        int i1 = tid;
        if (d2 < d1) { d1 = d2; i1 = tid + 512; }  // strict <: lower idx on tie
        #pragma unroll
        for (int off = 32; off; off >>= 1) {
          float vd = __shfl_xor(d1, off, 64);
          int vi = __shfl_xor(i1, off, 64);
          if (vd < d1 || (vd == d1 && vi < i1)) { d1 = vd; i1 = vi; }
        }
        if (lane == 0) { fwD[wv] = d1; fwI[wv] = i1; }
        __syncthreads();
        if (tid == 0) {
          float bd = fwD[0];
          int bi = fwI[0];
          #pragma unroll
          for (int w = 1; w < NW; ++w) {
            if (fwD[w] < bd || (fwD[w] == bd && fwI[w] < bi)) {
              bd = fwD[w]; bi = fwI[w];
            }
          }
          bcode[r] = bi;
        }
        __syncthreads();
      }
    }

    if (tid < TM)
      idx_out[(size_t)qi * MM + rowBase + tid] = (float)bcode[tid];

    // phase 5: STE update — FROZEN: t=fl(q-r); u=fl(r+t); r'=fl(r-u)
    const int codeB = bcode[r16];
    double lsum = 0.0;
    #pragma unroll
    for (int h = 0; h < 4; ++h) {
      const int d = d0 + h * 4;
      const float4 ev = *(const float4*)(cb + (size_t)codeB * DIMD + d);
      const float4 rv = *(const float4*)&residF[r16][d];
      float t0 = __fsub_rn(ev.x, rv.x), u0 = __fadd_rn(rv.x, t0);
      float t1 = __fsub_rn(ev.y, rv.y), u1 = __fadd_rn(rv.y, t1);
      float t2 = __fsub_rn(ev.z, rv.z), u2 = __fadd_rn(rv.z, t2);
      float t3 = __fsub_rn(ev.w, rv.w), u3 = __fadd_rn(rv.w, t3);
      *(float4*)&residF[r16][d] =
          make_float4(__fsub_rn(rv.x, u0), __fsub_rn(rv.y, u1),
                      __fsub_rn(rv.z, u2), __fsub_rn(rv.w, u3));
      lsum += (double)__fmul_rn(t0, t0) + (double)__fmul_rn(t1, t1) +
              (double)__fmul_rn(t2, t2) + (double)__fmul_rn(t3, t3);
    }
    #pragma unroll
    for (int off = 32; off; off >>= 1) lsum += __shfl_xor(lsum, off, 64);
    if (lane == 0) lossW[wv] = lsum;
    __syncthreads();   // orders residF writes before next stage's reads
    if (tid == 0) {
      double s = 0.0;
      #pragma unroll
      for (int w = 0; w < NW; ++w) s += lossW[w];
      atomicAdd(lossP + (size_t)qi * 64 + (blockIdx.x & 63), s);
    }
  }

  // epilogue: out_q = fl(x - resid_final)
  {
    const float* xp = x + (size_t)(rowBase + r16) * DIMD + d0;
    float* op = out_q + (size_t)(rowBase + r16) * DIMD + d0;
    #pragma unroll
    for (int h = 0; h < 4; ++h) {
      const float4 a = *(const float4*)(xp + h * 4);
      const float4 b = *(const float4*)&residF[r16][d0 + h * 4];
      *(float4*)(op + h * 4) =
          make_float4(__fsub_rn(a.x, b.x), __fsub_rn(a.y, b.y),
                      __fsub_rn(a.z, b.z), __fsub_rn(a.w, b.w));
    }
  }

  // folded k_loss: last block to finish sums lossP (device-scope atomics
  // both sides; __threadfence orders this block's lossP adds first).
  __syncthreads();
  if (tid == 0) {
    __threadfence();
    unsigned old = atomicAdd(doneCnt, 1u);
    cnt[0] = (old == (unsigned)(gridDim.x - 1)) ? 1 : 0;
  }
  __syncthreads();
  if (cnt[0] && tid < 64) {
    const int qi2 = tid >> 4;
    double s = 0.0;
    #pragma unroll
    for (int i = 0; i < 4; ++i)
      s += atomicAdd(lossP + (size_t)qi2 * 64 + (tid & 15) * 4 + i, 0.0);
    #pragma unroll
    for (int off = 8; off; off >>= 1) s += __shfl_down(s, off, 16);
    if ((tid & 15) == 0)
      out_loss[qi2] = (float)(s * (1.0 / (double)((size_t)MM * DIMD)));
  }
}

extern "C" void kernel_launch(void* const* d_in, const int* in_sizes, int n_in,
                              void* d_out, int out_size, void* d_ws, size_t ws_size,
                              hipStream_t stream) {
  const float* x = (const float*)d_in[0];        // [8,2048,256]
  const float* cb = (const float*)d_in[1];       // [4,1024,256]
  float* ws = (float*)d_ws;
  unsigned short* cbT = (unsigned short*)ws;     // 1,048,576 ushort (transposed)
  float* bK = ws + 524288;
  double* lossP = (double*)(ws + 528384);        // [QQ][64], byte off %8==0
  unsigned* done = (unsigned*)(ws + 528896);

  float* out = (float*)d_out;
  float* out_idx = out + (size_t)MM * DIMD;      // 4,194,304
  float* out_loss = out_idx + (size_t)QQ * MM;   // +65,536

  k_prep<<<dim3(QQ * NE / 8), dim3(256), 0, stream>>>(cb, cbT, bK, lossP, done);
  k_fused<<<dim3(MM / TM), dim3(512), 0, stream>>>(x, cbT, cb, bK, lossP,
                                                   done, out, out_idx, out_loss);
}